// Round 1
// baseline (8012.975 us; speedup 1.0000x reference)
//
#include <hip/hip_runtime.h>
#include <hip/hip_bf16.h>

#define H       512
#define BATCH   128
#define OUTLEN  1024
#define RROWS   16      // batch rows per group
#define CCOLS   16      // h-columns per block
#define NGROUP  8
#define NCOLBLK 32
#define NBLOCK  256
#define NTHREADS 384    // 6 waves: one per gate matrix
#define LDS_STRIDE 520  // 512 + 8 pad elems (16B) to break b128 bank aliasing

typedef __attribute__((ext_vector_type(8))) short short8;
typedef __attribute__((ext_vector_type(4))) float floatx4;

static __device__ __forceinline__ unsigned short f2bf(float f) {
    unsigned u = __builtin_bit_cast(unsigned, f);
    unsigned r = u + 0x7FFFu + ((u >> 16) & 1u);   // RNE
    return (unsigned short)(r >> 16);
}

__global__ void gru_init(const float* __restrict__ enc, int enc_len,
                         unsigned short* __restrict__ hbuf, int* __restrict__ flags) {
    int tid = blockIdx.x * blockDim.x + threadIdx.x;
    if (tid < BATCH * H) {
        int b = tid >> 9, k = tid & (H - 1);
        float v = enc[((size_t)b * enc_len + (enc_len - 1)) * H + k];
        hbuf[tid] = f2bf(v);                       // h_state[0] -> slot 0
    }
    if (tid < NBLOCK) flags[tid] = 0;
}

__launch_bounds__(NTHREADS, 1)
__global__ void gru_main(const float* __restrict__ enc, int enc_len,
                         const float* __restrict__ W_ih, const float* __restrict__ W_hh,
                         const float* __restrict__ b_ih, const float* __restrict__ b_hh,
                         float* __restrict__ out,
                         unsigned short* __restrict__ hbuf, int* __restrict__ flags) {
    __shared__ short hs[RROWS * LDS_STRIDE];       // bf16 bits of h_state[t], this group's rows
    __shared__ float gacc[6][RROWS * CCOLS];       // gate pre-activations
    __shared__ float state[RROWS * CCOLS];         // fp32 h tile owned by this block
    __shared__ float bias_i[3 * CCOLS];
    __shared__ float bias_h[3 * CCOLS];

    const int group  = blockIdx.x & 7;             // XCD-swizzle friendly: group members spread %8
    const int colblk = blockIdx.x >> 3;
    const int row0   = group * RROWS;
    const int col0   = colblk * CCOLS;
    const int tid    = threadIdx.x;
    const int wid    = tid >> 6;                   // 0..5 = gate matrix
    const int lane   = tid & 63;
    const int l15    = lane & 15;
    const int quad   = lane >> 4;

    // ---- one-time init: weights -> VGPR B-fragments (B[n=lane&15][k=quad*8+j]) ----
    short8 wfrag[16];
    {
        const float* Wm = (wid < 3) ? W_ih : W_hh;
        const int gb = (wid < 3 ? wid : wid - 3) * H;
        const float* wrow = Wm + (size_t)(gb + col0 + l15) * H + quad * 8;
        #pragma unroll
        for (int kk = 0; kk < 16; ++kk) {
            short8 f;
            #pragma unroll
            for (int j = 0; j < 8; ++j)
                f[j] = (short)f2bf(wrow[kk * 32 + j]);
            wfrag[kk] = f;
        }
    }
    if (tid < 3 * CCOLS) {
        int g = tid >> 4, c = tid & 15;
        bias_i[tid] = b_ih[g * H + col0 + c];
        bias_h[tid] = b_hh[g * H + col0 + c];
    }
    if (tid < RROWS * CCOLS) {
        int r = tid >> 4, c = tid & 15;
        state[tid] = enc[((size_t)(row0 + r) * enc_len + (enc_len - 1)) * H + col0 + c];
    }
    __syncthreads();

    for (int t = 0; t < OUTLEN; ++t) {
        // ---- wait until h_state[t] is visible (32 producer flags of this group) ----
        if (t > 0) {
            if (tid < NCOLBLK) {
                int* fp = flags + group + 8 * tid;
                while (__hip_atomic_load(fp, __ATOMIC_RELAXED, __HIP_MEMORY_SCOPE_AGENT) < t) { }
                __builtin_amdgcn_fence(__ATOMIC_ACQUIRE, "agent");  // invalidate L1/L2 (CU/XCD-wide)
            }
            __syncthreads();
        }

        // ---- stage h_state[t] (16 rows x 512 cols bf16) into LDS ----
        {
            const unsigned short* src = hbuf + (size_t)(t & 1) * (BATCH * H) + (size_t)row0 * H;
            for (int i = tid; i < RROWS * H / 8; i += NTHREADS) {
                int r = i >> 6, c8 = i & 63;
                short8 v = *reinterpret_cast<const short8*>(src + r * H + c8 * 8);
                *reinterpret_cast<short8*>(&hs[r * LDS_STRIDE + c8 * 8]) = v;
            }
        }
        __syncthreads();

        // ---- MFMA: this wave's gate tile (16x16, K=512), 2 interleaved chains ----
        floatx4 acc0 = {0.f, 0.f, 0.f, 0.f}, acc1 = {0.f, 0.f, 0.f, 0.f};
        if (t > 0 || wid >= 3) {                   // t==0: x=0 -> i-gates are bias-only
            const short* arow = hs + l15 * LDS_STRIDE + quad * 8;
            #pragma unroll
            for (int kk = 0; kk < 16; kk += 2) {
                short8 a0 = *reinterpret_cast<const short8*>(arow + kk * 32);
                short8 a1 = *reinterpret_cast<const short8*>(arow + (kk + 1) * 32);
                acc0 = __builtin_amdgcn_mfma_f32_16x16x32_bf16(a0, wfrag[kk],     acc0, 0, 0, 0);
                acc1 = __builtin_amdgcn_mfma_f32_16x16x32_bf16(a1, wfrag[kk + 1], acc1, 0, 0, 0);
            }
        }
        #pragma unroll
        for (int i = 0; i < 4; ++i)               // C/D layout: col=lane&15, row=quad*4+i
            gacc[wid][(quad * 4 + i) * CCOLS + l15] = acc0[i] + acc1[i];
        __syncthreads();

        // ---- fused gate epilogue (fp32), update state, write output ----
        if (tid < RROWS * CCOLS) {
            int r = tid >> 4, c = tid & 15;
            float rr = gacc[0][tid] + gacc[3][tid] + bias_i[c] + bias_h[c];
            rr = 1.f / (1.f + __expf(-rr));
            float zz = gacc[1][tid] + gacc[4][tid] + bias_i[16 + c] + bias_h[16 + c];
            zz = 1.f / (1.f + __expf(-zz));
            float nx = gacc[2][tid] + bias_i[32 + c] + rr * (gacc[5][tid] + bias_h[32 + c]);
            nx = fminf(fmaxf(nx, -15.f), 15.f);
            float e  = __expf(-2.f * nx);
            float nn = (1.f - e) / (1.f + e);
            float hnew = (1.f - zz) * nn + zz * state[tid];
            state[tid] = hnew;
            out[((size_t)t * BATCH + row0 + r) * H + col0 + c] = hnew;
        }
        __syncthreads();

        // ---- publish h_state[t+1] tile as bf16 (agent-scope atomics, bypass L1) ----
        if (tid < RROWS * CCOLS / 2) {
            int r = tid >> 3, cp = tid & 7;
            float v0 = state[r * CCOLS + cp * 2];
            float v1 = state[r * CCOLS + cp * 2 + 1];
            unsigned val = (unsigned)f2bf(v0) | ((unsigned)f2bf(v1) << 16);
            unsigned* dst = (unsigned*)(hbuf + (size_t)((t + 1) & 1) * (BATCH * H)
                                        + (size_t)(row0 + r) * H + col0 + cp * 2);
            __hip_atomic_store(dst, val, __ATOMIC_RELAXED, __HIP_MEMORY_SCOPE_AGENT);
        }
        __syncthreads();                           // compiler drains vmcnt(0) before s_barrier
        if (tid == 0)
            __hip_atomic_store(flags + blockIdx.x, t + 1, __ATOMIC_RELEASE, __HIP_MEMORY_SCOPE_AGENT);
    }
}

extern "C" void kernel_launch(void* const* d_in, const int* in_sizes, int n_in,
                              void* d_out, int out_size, void* d_ws, size_t ws_size,
                              hipStream_t stream) {
    const float* enc  = (const float*)d_in[0];
    const float* W_ih = (const float*)d_in[1];
    const float* W_hh = (const float*)d_in[2];
    const float* b_ih = (const float*)d_in[3];
    const float* b_hh = (const float*)d_in[4];
    float* out = (float*)d_out;
    int enc_len = in_sizes[0] / (BATCH * H);       // 100

    unsigned short* hbuf = (unsigned short*)d_ws;              // 2 slots x 128x512 bf16 = 256 KB
    int* flags = (int*)((char*)d_ws + (size_t)2 * BATCH * H * sizeof(unsigned short));

    hipLaunchKernelGGL(gru_init, dim3(256), dim3(256), 0, stream, enc, enc_len, hbuf, flags);

    void* args[] = { (void*)&enc, (void*)&enc_len, (void*)&W_ih, (void*)&W_hh,
                     (void*)&b_ih, (void*)&b_hh, (void*)&out, (void*)&hbuf, (void*)&flags };
    hipLaunchCooperativeKernel((const void*)gru_main, dim3(NBLOCK), dim3(NTHREADS),
                               args, 0, stream);
}

// Round 4
// 4308.255 us; speedup vs baseline: 1.8599x; 1.8599x over previous
//
#include <hip/hip_runtime.h>
#include <hip/hip_bf16.h>

#define H       512
#define BATCH   128
#define OUTLEN  1024
#define RROWS   16      // batch rows per group
#define CCOLS   16      // h-columns per block
#define NGROUP  8
#define NCOLBLK 32
#define NBLOCK  256
#define NTHREADS 384    // 6 waves: i_r, i_z, i_n, h_r, h_z, h_n
#define LSTR    520     // LDS row stride (shorts): 512 + 8 pad

typedef __attribute__((ext_vector_type(8))) short short8;
typedef __attribute__((ext_vector_type(4))) float floatx4;

static __device__ __forceinline__ unsigned short f2bf(float f) {
    unsigned u = __builtin_bit_cast(unsigned, f);
    unsigned r = u + 0x7FFFu + ((u >> 16) & 1u);   // RNE
    return (unsigned short)(r >> 16);
}

__global__ void gru_init(const float* __restrict__ enc, int enc_len,
                         unsigned short* __restrict__ hbuf, int* __restrict__ flags) {
    int tid = blockIdx.x * blockDim.x + threadIdx.x;
    if (tid < BATCH * H) {
        int b = tid >> 9, k = tid & (H - 1);
        float v = enc[((size_t)b * enc_len + (enc_len - 1)) * H + k];
        hbuf[tid] = f2bf(v);                       // h_state[0] -> slot 0
    }
    if (tid < NBLOCK) flags[tid] = 0;              // d_ws is poisoned 0xAA each launch
}

__launch_bounds__(NTHREADS, 1)
__global__ void gru_main(const float* __restrict__ enc, int enc_len,
                         const float* __restrict__ W_ih, const float* __restrict__ W_hh,
                         const float* __restrict__ b_ih, const float* __restrict__ b_hh,
                         float* __restrict__ out,
                         unsigned short* __restrict__ hbuf, int* __restrict__ flags) {
    __shared__ __align__(16) short hs[RROWS * LSTR];   // h_{t-1} tile, bf16 bits
    __shared__ float gacc[6][RROWS * CCOLS];           // gate pre-activations
    __shared__ float bias_i[3 * CCOLS];
    __shared__ float bias_h[3 * CCOLS];

    const int group  = blockIdx.x & 7;
    const int colblk = blockIdx.x >> 3;
    const int row0   = group * RROWS;
    const int col0   = colblk * CCOLS;
    const int tid    = threadIdx.x;
    const int wid    = tid >> 6;                   // 0..5 = gate matrix
    const int lane   = tid & 63;
    const int l15    = lane & 15;
    const int quad   = lane >> 4;

    // ---- one-time: weights -> VGPR B-fragments (B[n=lane&15][k=quad*8+j]) ----
    short8 wfrag[16];
    {
        const float* Wm = (wid < 3) ? W_ih : W_hh;
        const int gb = (wid < 3 ? wid : wid - 3) * H;
        const float* wrow = Wm + (size_t)(gb + col0 + l15) * H + quad * 8;
        #pragma unroll
        for (int kk = 0; kk < 16; ++kk) {
            short8 f;
            #pragma unroll
            for (int j = 0; j < 8; ++j)
                f[j] = (short)f2bf(wrow[kk * 32 + j]);
            wfrag[kk] = f;
        }
    }
    if (tid < 3 * CCOLS) {
        int g = tid >> 4, c = tid & 15;
        bias_i[tid] = b_ih[g * H + col0 + c];
        bias_h[tid] = b_hh[g * H + col0 + c];
    }
    // ---- fp32 recurrent state in registers: tid<128 owns (row r, cols 2c2, 2c2+1) ----
    float st0 = 0.f, st1 = 0.f;
    if (tid < 128) {
        int r = tid >> 3, c2 = tid & 7;
        const float* e = enc + ((size_t)(row0 + r) * enc_len + (enc_len - 1)) * H + col0 + 2 * c2;
        st0 = e[0];
        st1 = e[1];
    }
    __syncthreads();

    const unsigned long long* hb64 = (const unsigned long long*)hbuf;  // row = 128 u64 chunks
    unsigned int* hb32 = (unsigned int*)hbuf;                          // row = 256 u32

    for (int t = 0; t < OUTLEN; ++t) {
        // ---- wait for h_t to be published (t=0: staged by gru_init, stream-ordered) ----
        if (t > 0 && tid < 256 && lane < 32) {     // staging waves poll their group's 32 producers
            int* fp = flags + group + 8 * lane;
            while (__hip_atomic_load(fp, __ATOMIC_RELAXED, __HIP_MEMORY_SCOPE_AGENT) < t) { }
        }
        // ---- stage h_t tile (16 rows x 512 bf16 = 2048 u64 chunks) via bypassing loads ----
        if (tid < 256) {
            const unsigned long long* sp = hb64 + (size_t)(t & 1) * 16384 + (size_t)row0 * 128;
            unsigned long long vv[8];
            #pragma unroll
            for (int j = 0; j < 8; ++j) {
                int p = j * 256 + tid;             // 0..2047; r = p>>7 (row), c = p&127 (u64 col)
                vv[j] = __hip_atomic_load(sp + (p >> 7) * 128 + (p & 127),
                                          __ATOMIC_RELAXED, __HIP_MEMORY_SCOPE_AGENT);
            }
            #pragma unroll
            for (int j = 0; j < 8; ++j) {
                int p = j * 256 + tid;
                *reinterpret_cast<unsigned long long*>(hs + (p >> 7) * LSTR + (p & 127) * 4) = vv[j];
            }
        }
        __syncthreads();                           // B1: tile staged

        // ---- MFMA: this wave's gate tile (16x16, K=512), 2 interleaved chains ----
        floatx4 acc0 = {0.f, 0.f, 0.f, 0.f}, acc1 = {0.f, 0.f, 0.f, 0.f};
        if (t > 0 || wid >= 3) {                   // t==0: x=0 -> i-gate matmuls are zero
            const short* arow = hs + l15 * LSTR + quad * 8;
            #pragma unroll
            for (int kk = 0; kk < 16; kk += 2) {
                short8 a0 = *reinterpret_cast<const short8*>(arow + kk * 32);
                short8 a1 = *reinterpret_cast<const short8*>(arow + (kk + 1) * 32);
                acc0 = __builtin_amdgcn_mfma_f32_16x16x32_bf16(a0, wfrag[kk],     acc0, 0, 0, 0);
                acc1 = __builtin_amdgcn_mfma_f32_16x16x32_bf16(a1, wfrag[kk + 1], acc1, 0, 0, 0);
            }
        }
        #pragma unroll
        for (int i = 0; i < 4; ++i)                // C/D layout: col=lane&15, row=quad*4+i
            gacc[wid][(quad * 4 + i) * CCOLS + l15] = acc0[i] + acc1[i];
        __syncthreads();                           // B2: gaccs ready

        // ---- fused epilogue: gates, state update, publish (first), output ----
        if (tid < 128) {
            int r = tid >> 3, c2 = tid & 7;
            int i0 = r * CCOLS + 2 * c2, c = 2 * c2;
            float rr0 = gacc[0][i0]     + gacc[3][i0]     + bias_i[c]     + bias_h[c];
            float rr1 = gacc[0][i0 + 1] + gacc[3][i0 + 1] + bias_i[c + 1] + bias_h[c + 1];
            rr0 = 1.f / (1.f + __expf(-rr0));
            rr1 = 1.f / (1.f + __expf(-rr1));
            float zz0 = gacc[1][i0]     + gacc[4][i0]     + bias_i[16 + c]     + bias_h[16 + c];
            float zz1 = gacc[1][i0 + 1] + gacc[4][i0 + 1] + bias_i[16 + c + 1] + bias_h[16 + c + 1];
            zz0 = 1.f / (1.f + __expf(-zz0));
            zz1 = 1.f / (1.f + __expf(-zz1));
            float nx0 = gacc[2][i0]     + bias_i[32 + c]     + rr0 * (gacc[5][i0]     + bias_h[32 + c]);
            float nx1 = gacc[2][i0 + 1] + bias_i[32 + c + 1] + rr1 * (gacc[5][i0 + 1] + bias_h[32 + c + 1]);
            nx0 = fminf(fmaxf(nx0, -15.f), 15.f);
            nx1 = fminf(fmaxf(nx1, -15.f), 15.f);
            float e0 = __expf(-2.f * nx0), e1 = __expf(-2.f * nx1);
            float nn0 = (1.f - e0) / (1.f + e0);
            float nn1 = (1.f - e1) / (1.f + e1);
            st0 = (1.f - zz0) * nn0 + zz0 * st0;
            st1 = (1.f - zz1) * nn1 + zz1 * st1;
            // publish h_{t+1} pair to LLC first (critical path), bypassing store
            unsigned val = (unsigned)f2bf(st0) | ((unsigned)f2bf(st1) << 16);
            unsigned* dst = hb32 + (size_t)((t + 1) & 1) * 32768
                          + (size_t)(row0 + r) * 256 + colblk * 8 + c2;
            __hip_atomic_store(dst, val, __ATOMIC_RELAXED, __HIP_MEMORY_SCOPE_AGENT);
            // output (cached fp32 store)
            float* op = out + ((size_t)t * BATCH + row0 + r) * H + col0 + 2 * c2;
            op[0] = st0;
            op[1] = st1;
        }
        __syncthreads();                           // B3: vmcnt(0) drain -> publishes at LLC
        if (tid == 0)
            __hip_atomic_store(flags + blockIdx.x, t + 1,
                               __ATOMIC_RELAXED, __HIP_MEMORY_SCOPE_AGENT);
    }
}

extern "C" void kernel_launch(void* const* d_in, const int* in_sizes, int n_in,
                              void* d_out, int out_size, void* d_ws, size_t ws_size,
                              hipStream_t stream) {
    const float* enc  = (const float*)d_in[0];
    const float* W_ih = (const float*)d_in[1];
    const float* W_hh = (const float*)d_in[2];
    const float* b_ih = (const float*)d_in[3];
    const float* b_hh = (const float*)d_in[4];
    float* out = (float*)d_out;
    int enc_len = in_sizes[0] / (BATCH * H);       // 100

    unsigned short* hbuf = (unsigned short*)d_ws;  // 2 slots x 128x512 bf16 = 256 KB
    int* flags = (int*)((char*)d_ws + (size_t)2 * BATCH * H * sizeof(unsigned short));

    hipLaunchKernelGGL(gru_init, dim3(256), dim3(256), 0, stream, enc, enc_len, hbuf, flags);

    void* args[] = { (void*)&enc, (void*)&enc_len, (void*)&W_ih, (void*)&W_hh,
                     (void*)&b_ih, (void*)&b_hh, (void*)&out, (void*)&hbuf, (void*)&flags };
    hipError_t err = hipLaunchCooperativeKernel((const void*)gru_main, dim3(NBLOCK),
                                                dim3(NTHREADS), args, 0, stream);
    if (err != hipSuccess) {
        // Fallback: plain launch. 256 blocks <= 256 CUs at >=1 block/CU occupancy
        // (__launch_bounds__(384,1), ~100 VGPRs) => all blocks co-resident.
        hipLaunchKernelGGL(gru_main, dim3(NBLOCK), dim3(NTHREADS), 0, stream,
                           enc, enc_len, W_ih, W_hh, b_ih, b_hh, out, hbuf, flags);
    }
}

// Round 6
// 2709.425 us; speedup vs baseline: 2.9574x; 1.5901x over previous
//
#include <hip/hip_runtime.h>
#include <hip/hip_bf16.h>

#define H        512
#define BATCH    128
#define OUTLEN   1024
#define RROWS    16     // batch rows per group
#define CBCOLS   64     // h-columns per block
#define NBLOCK   64     // 8 groups x 8 col-blocks
#define NTH      512    // 8 waves; wave w: mat (w>>1), col-tile pair (w&1)
#define LSTR     520    // LDS row stride (shorts): 512 + 8 pad
#define GSTR     68     // gacc row stride (floats): 64 + 4 pad

typedef __attribute__((ext_vector_type(8))) short short8;
typedef __attribute__((ext_vector_type(4))) float floatx4;
typedef __attribute__((ext_vector_type(2))) float floatx2;

static __device__ __forceinline__ unsigned short f2bf(float f) {
    unsigned u = __builtin_bit_cast(unsigned, f);
    unsigned r = u + 0x7FFFu + ((u >> 16) & 1u);   // RNE
    return (unsigned short)(r >> 16);
}
static __device__ __forceinline__ float sigm(float x) { return 1.f / (1.f + __expf(-x)); }
static __device__ __forceinline__ float tanhc(float x) {
    x = fminf(fmaxf(x, -15.f), 15.f);
    float e = __expf(-2.f * x);
    return (1.f - e) / (1.f + e);
}

// Step-0 peel: h1 = GRUcell(x=0, h0) in fp32. Writes out[0], publishes bf16 h1
// into hbuf slot 1 AND fp32 h1 into h1buf (for the main kernel's register state).
// 64 blocks x 512 threads; block handles 2 batch rows; zeroes flags.
__global__ void gru_init(const float* __restrict__ enc, int enc_len,
                         const float* __restrict__ W_hh,
                         const float* __restrict__ b_ih, const float* __restrict__ b_hh,
                         float* __restrict__ out, unsigned short* __restrict__ hbuf,
                         float* __restrict__ h1buf, int* __restrict__ flags) {
    __shared__ float h0[2][H];
    const int tid = threadIdx.x;
    const int b0 = blockIdx.x * 2;
    for (int i = tid; i < 2 * H; i += NTH) {
        int r = i >> 9, k = i & (H - 1);
        h0[r][k] = enc[((size_t)(b0 + r) * enc_len + (enc_len - 1)) * H + k];
    }
    __syncthreads();
    const int c = tid;  // one output column per thread
    const float4* wr = (const float4*)(W_hh + (size_t)(0 * H + c) * H);
    const float4* wz = (const float4*)(W_hh + (size_t)(1 * H + c) * H);
    const float4* wn = (const float4*)(W_hh + (size_t)(2 * H + c) * H);
    float dr0 = 0.f, dz0 = 0.f, dn0 = 0.f, dr1 = 0.f, dz1 = 0.f, dn1 = 0.f;
    #pragma unroll 4
    for (int k4 = 0; k4 < H / 4; ++k4) {
        float4 a = wr[k4], b = wz[k4], d = wn[k4];
        const float* p0 = &h0[0][k4 * 4];
        const float* p1 = &h0[1][k4 * 4];
        dr0 += a.x * p0[0] + a.y * p0[1] + a.z * p0[2] + a.w * p0[3];
        dz0 += b.x * p0[0] + b.y * p0[1] + b.z * p0[2] + b.w * p0[3];
        dn0 += d.x * p0[0] + d.y * p0[1] + d.z * p0[2] + d.w * p0[3];
        dr1 += a.x * p1[0] + a.y * p1[1] + a.z * p1[2] + a.w * p1[3];
        dz1 += b.x * p1[0] + b.y * p1[1] + b.z * p1[2] + b.w * p1[3];
        dn1 += d.x * p1[0] + d.y * p1[1] + d.z * p1[2] + d.w * p1[3];
    }
    const float bir = b_ih[c], biz = b_ih[H + c], bin = b_ih[2 * H + c];
    const float bhr = b_hh[c], bhz = b_hh[H + c], bhn = b_hh[2 * H + c];
    unsigned short* hb1 = hbuf + (size_t)BATCH * H;    // slot 1
    {
        float r0 = sigm(bir + dr0 + bhr);
        float z0 = sigm(biz + dz0 + bhz);
        float n0 = tanhc(bin + r0 * (dn0 + bhn));
        float h1 = (1.f - z0) * n0 + z0 * h0[0][c];
        out[(size_t)b0 * H + c] = h1;                  // out[t=0], row b0
        h1buf[(size_t)b0 * H + c] = h1;
        __hip_atomic_store(hb1 + (size_t)b0 * H + c, f2bf(h1),
                           __ATOMIC_RELAXED, __HIP_MEMORY_SCOPE_AGENT);
    }
    {
        float r1 = sigm(bir + dr1 + bhr);
        float z1 = sigm(biz + dz1 + bhz);
        float n1 = tanhc(bin + r1 * (dn1 + bhn));
        float h1 = (1.f - z1) * n1 + z1 * h0[1][c];
        out[(size_t)(b0 + 1) * H + c] = h1;
        h1buf[(size_t)(b0 + 1) * H + c] = h1;
        __hip_atomic_store(hb1 + (size_t)(b0 + 1) * H + c, f2bf(h1),
                           __ATOMIC_RELAXED, __HIP_MEMORY_SCOPE_AGENT);
    }
    if (blockIdx.x == 0 && tid < NBLOCK)
        __hip_atomic_store(flags + tid, 0, __ATOMIC_RELAXED, __HIP_MEMORY_SCOPE_AGENT);
}

__launch_bounds__(NTH, 1)
__global__ void gru_main(const float* __restrict__ enc, int enc_len,
                         const float* __restrict__ W_ih, const float* __restrict__ W_hh,
                         const float* __restrict__ b_ih, const float* __restrict__ b_hh,
                         float* __restrict__ out,
                         unsigned short* __restrict__ hbuf, const float* __restrict__ h1buf,
                         int* __restrict__ flags) {
    __shared__ __align__(16) short hs[RROWS * LSTR];   // h_t tile (16 x 512 bf16)
    __shared__ float gacc[4][RROWS * GSTR];            // rsum, zsum, i_n, h_n pre-acts
    __shared__ float bias[4][CBCOLS];

    const int group  = blockIdx.x & 7;
    const int colblk = blockIdx.x >> 3;
    const int row0   = group * RROWS;
    const int col0   = colblk * CBCOLS;
    const int tid    = threadIdx.x;
    const int wid    = tid >> 6;                       // 0..7
    const int lane   = tid & 63;
    const int l15    = lane & 15;
    const int quad   = lane >> 4;
    const int mat    = wid >> 1;                       // 0:rsum 1:zsum 2:i_n 3:h_n
    const int ct0    = (wid & 1) * 2;                  // this wave's two 16-col tiles

    // ---- one-time: weights -> VGPR B-fragments (presummed r/z) ----
    short8 wf0[16], wf1[16];
    #pragma unroll
    for (int tt = 0; tt < 2; ++tt) {
        const int gc = col0 + (ct0 + tt) * 16 + l15;   // global output column
        const float* a;
        const float* b = nullptr;
        if      (mat == 0) { a = W_ih + (size_t)gc * H;           b = W_hh + (size_t)gc * H; }
        else if (mat == 1) { a = W_ih + (size_t)(H + gc) * H;     b = W_hh + (size_t)(H + gc) * H; }
        else if (mat == 2) { a = W_ih + (size_t)(2 * H + gc) * H; }
        else               { a = W_hh + (size_t)(2 * H + gc) * H; }
        a += quad * 8;
        if (b) b += quad * 8;
        #pragma unroll
        for (int kk = 0; kk < 16; ++kk) {
            short8 f;
            #pragma unroll
            for (int j = 0; j < 8; ++j) {
                float v = a[kk * 32 + j];
                if (b) v += b[kk * 32 + j];
                f[j] = (short)f2bf(v);
            }
            if (tt == 0) wf0[kk] = f; else wf1[kk] = f;
        }
    }
    if (tid < 4 * CBCOLS) {
        int m = tid >> 6, c = tid & 63, gc = col0 + c;
        float v;
        if      (m == 0) v = b_ih[gc] + b_hh[gc];
        else if (m == 1) v = b_ih[H + gc] + b_hh[H + gc];
        else if (m == 2) v = b_ih[2 * H + gc];
        else             v = b_hh[2 * H + gc];
        bias[m][c] = v;
    }
    // ---- fp32 recurrent state = h1 (R5 bug: was h0) ----
    const int er = tid >> 5, ep = tid & 31;
    float st0, st1;
    {
        const float* p = h1buf + (size_t)(row0 + er) * H + col0 + 2 * ep;
        st0 = p[0];
        st1 = p[1];
    }
    __syncthreads();

    const unsigned long long* hb64 = (const unsigned long long*)hbuf;  // slot = 16384 u64
    unsigned int* hb32 = (unsigned int*)hbuf;                          // slot = 32768 u32

    for (int t = 1; t < OUTLEN; ++t) {
        // ---- wait for h_t (t==1: published by gru_init, stream-ordered) ----
        if (t > 1 && lane < 8) {                       // every wave polls its 8 producers
            int* fp = flags + lane * 8 + group;
            while (__hip_atomic_load(fp, __ATOMIC_RELAXED, __HIP_MEMORY_SCOPE_AGENT) < t) { }
        }
        // ---- stage h_t tile (16 x 512 bf16 = 2048 u64) via LLC-bypassing loads ----
        {
            const unsigned long long* sp = hb64 + (size_t)(t & 1) * 16384 + (size_t)row0 * 128;
            unsigned long long vv[4];
            #pragma unroll
            for (int j = 0; j < 4; ++j)
                vv[j] = __hip_atomic_load(sp + j * NTH + tid,
                                          __ATOMIC_RELAXED, __HIP_MEMORY_SCOPE_AGENT);
            #pragma unroll
            for (int j = 0; j < 4; ++j) {
                int p = j * NTH + tid;
                *reinterpret_cast<unsigned long long*>(hs + (p >> 7) * LSTR + (p & 127) * 4) = vv[j];
            }
        }
        __syncthreads();                               // B1: tile staged

        // ---- MFMA: two 16x16 tiles per wave, K=512, shared A-frags ----
        floatx4 acc00 = {0.f,0.f,0.f,0.f}, acc01 = {0.f,0.f,0.f,0.f};
        floatx4 acc10 = {0.f,0.f,0.f,0.f}, acc11 = {0.f,0.f,0.f,0.f};
        {
            const short* arow = hs + l15 * LSTR + quad * 8;
            #pragma unroll
            for (int kk = 0; kk < 16; kk += 2) {
                short8 a0 = *reinterpret_cast<const short8*>(arow + kk * 32);
                short8 a1 = *reinterpret_cast<const short8*>(arow + (kk + 1) * 32);
                acc00 = __builtin_amdgcn_mfma_f32_16x16x32_bf16(a0, wf0[kk],     acc00, 0, 0, 0);
                acc10 = __builtin_amdgcn_mfma_f32_16x16x32_bf16(a0, wf1[kk],     acc10, 0, 0, 0);
                acc01 = __builtin_amdgcn_mfma_f32_16x16x32_bf16(a1, wf0[kk + 1], acc01, 0, 0, 0);
                acc11 = __builtin_amdgcn_mfma_f32_16x16x32_bf16(a1, wf1[kk + 1], acc11, 0, 0, 0);
            }
        }
        #pragma unroll
        for (int i = 0; i < 4; ++i) {                  // C/D: col=lane&15, row=quad*4+i
            gacc[mat][(quad * 4 + i) * GSTR + ct0 * 16 + l15]       = acc00[i] + acc01[i];
            gacc[mat][(quad * 4 + i) * GSTR + (ct0 + 1) * 16 + l15] = acc10[i] + acc11[i];
        }
        __syncthreads();                               // B2: gaccs ready

        // ---- fused epilogue: all 512 threads, 2 columns each ----
        {
            const int i0 = er * GSTR + 2 * ep, c = 2 * ep;
            float rr0 = sigm(gacc[0][i0]     + bias[0][c]);
            float rr1 = sigm(gacc[0][i0 + 1] + bias[0][c + 1]);
            float zz0 = sigm(gacc[1][i0]     + bias[1][c]);
            float zz1 = sigm(gacc[1][i0 + 1] + bias[1][c + 1]);
            float nn0 = tanhc(gacc[2][i0]     + bias[2][c]     + rr0 * (gacc[3][i0]     + bias[3][c]));
            float nn1 = tanhc(gacc[2][i0 + 1] + bias[2][c + 1] + rr1 * (gacc[3][i0 + 1] + bias[3][c + 1]));
            st0 = (1.f - zz0) * nn0 + zz0 * st0;
            st1 = (1.f - zz1) * nn1 + zz1 * st1;
            // publish h_{t+1} pair to LLC (bypassing store) -- critical path
            unsigned val = (unsigned)f2bf(st0) | ((unsigned)f2bf(st1) << 16);
            __hip_atomic_store(hb32 + (size_t)((t + 1) & 1) * 32768
                                    + (size_t)(row0 + er) * 256 + (col0 >> 1) + ep,
                               val, __ATOMIC_RELAXED, __HIP_MEMORY_SCOPE_AGENT);
        }
        __syncthreads();                               // B3: vmcnt(0) drain -> publishes at LLC
        if (tid == 0)
            __hip_atomic_store(flags + blockIdx.x, t + 1,
                               __ATOMIC_RELAXED, __HIP_MEMORY_SCOPE_AGENT);
        // ---- deferred output store (off critical path) ----
        {
            floatx2 o = {st0, st1};
            *reinterpret_cast<floatx2*>(out + ((size_t)t * BATCH + row0 + er) * H + col0 + 2 * ep) = o;
        }
    }
}

extern "C" void kernel_launch(void* const* d_in, const int* in_sizes, int n_in,
                              void* d_out, int out_size, void* d_ws, size_t ws_size,
                              hipStream_t stream) {
    const float* enc  = (const float*)d_in[0];
    const float* W_ih = (const float*)d_in[1];
    const float* W_hh = (const float*)d_in[2];
    const float* b_ih = (const float*)d_in[3];
    const float* b_hh = (const float*)d_in[4];
    float* out = (float*)d_out;
    int enc_len = in_sizes[0] / (BATCH * H);       // 100

    unsigned short* hbuf = (unsigned short*)d_ws;  // 2 slots x 128x512 bf16 = 256 KB
    int* flags = (int*)((char*)d_ws + (size_t)2 * BATCH * H * sizeof(unsigned short));
    float* h1buf = (float*)((char*)flags + 256);   // fp32 h1, 256 KB

    hipLaunchKernelGGL(gru_init, dim3(NBLOCK), dim3(NTH), 0, stream,
                       enc, enc_len, W_hh, b_ih, b_hh, out, hbuf, h1buf, flags);

    void* args[] = { (void*)&enc, (void*)&enc_len, (void*)&W_ih, (void*)&W_hh,
                     (void*)&b_ih, (void*)&b_hh, (void*)&out, (void*)&hbuf,
                     (void*)&h1buf, (void*)&flags };
    hipError_t err = hipLaunchCooperativeKernel((const void*)gru_main, dim3(NBLOCK),
                                                dim3(NTH), args, 0, stream);
    if (err != hipSuccess) {
        // Fallback: 64 blocks <= 256 CUs at 1 block/CU => co-resident.
        hipLaunchKernelGGL(gru_main, dim3(NBLOCK), dim3(NTH), 0, stream,
                           enc, enc_len, W_ih, W_hh, b_ih, b_hh, out, hbuf, h1buf, flags);
    }
}